// Round 9
// baseline (122.629 us; speedup 1.0000x reference)
//
#include <hip/hip_runtime.h>

#define T_TOKENS 8192
#define DMODEL   1024
#define NEXP     8

#define BM 128   // tokens per tile
#define BN 128   // features per tile
#define BK 32    // k per step (32 -> dbuf fits in 32 KB, 4 blocks/CU)
#define NSTEP (DMODEL / BK)

typedef float f32x4  __attribute__((ext_vector_type(4)));
typedef short short8 __attribute__((ext_vector_type(8)));

__device__ __forceinline__ unsigned short f32_to_bf16(float f) {
    unsigned int u = __builtin_bit_cast(unsigned int, f);
    unsigned int r = 0x7FFFu + ((u >> 16) & 1u);
    return (unsigned short)((u + r) >> 16);
}

// ---------------------------------------------------------------------------
// Kernel 1 (fused): blocks [0,2048) = gating (fp32 logits, top-2, x->bf16);
// blocks [2048,4096) = We [E][d][f] fp32 -> wt [E][f][d] bf16 transpose.
// Uniform per-block branch; saves a launch and overlaps the two streams.
// ---------------------------------------------------------------------------
__global__ __launch_bounds__(256)
void prep(const float* __restrict__ x, const float* __restrict__ Wg,
          const float* __restrict__ We,
          unsigned short* __restrict__ xb, unsigned short* __restrict__ wt,
          int* __restrict__ top_e, float* __restrict__ top_w) {
    __shared__ unsigned short tile[64][72];
    const int bid = blockIdx.x;

    if (bid < 2048) {
        // ---- gating: one wave per token, 4 tokens/block ----
        const int wave = threadIdx.x >> 6;
        const int lane = threadIdx.x & 63;
        const int t = bid * 4 + wave;

        float lg[8];
        #pragma unroll
        for (int e = 0; e < 8; ++e) lg[e] = 0.0f;

        const float* xr = x + (size_t)t * DMODEL;
        unsigned short* xo = xb + (size_t)t * DMODEL;

        #pragma unroll
        for (int j = 0; j < 4; ++j) {
            const int d = j * 256 + lane * 4;
            float4 xv = *reinterpret_cast<const float4*>(xr + d);
            ushort4 o;
            o.x = f32_to_bf16(xv.x);
            o.y = f32_to_bf16(xv.y);
            o.z = f32_to_bf16(xv.z);
            o.w = f32_to_bf16(xv.w);
            *reinterpret_cast<ushort4*>(xo + d) = o;
            const float xs[4] = {xv.x, xv.y, xv.z, xv.w};
            #pragma unroll
            for (int c = 0; c < 4; ++c) {
                const float4 wlo = *reinterpret_cast<const float4*>(Wg + (size_t)(d + c) * 8);
                const float4 whi = *reinterpret_cast<const float4*>(Wg + (size_t)(d + c) * 8 + 4);
                lg[0] += xs[c] * wlo.x;  lg[1] += xs[c] * wlo.y;
                lg[2] += xs[c] * wlo.z;  lg[3] += xs[c] * wlo.w;
                lg[4] += xs[c] * whi.x;  lg[5] += xs[c] * whi.y;
                lg[6] += xs[c] * whi.z;  lg[7] += xs[c] * whi.w;
            }
        }
        #pragma unroll
        for (int off = 1; off < 64; off <<= 1) {
            #pragma unroll
            for (int e = 0; e < 8; ++e) lg[e] += __shfl_xor(lg[e], off);
        }

        if (lane == 0) {
            int i1 = 0; float v1 = lg[0];
            #pragma unroll
            for (int e = 1; e < 8; ++e) if (lg[e] > v1) { v1 = lg[e]; i1 = e; }
            int i2 = -1; float v2 = -1e30f;
            #pragma unroll
            for (int e = 0; e < 8; ++e) if (e != i1 && lg[e] > v2) { v2 = lg[e]; i2 = e; }
            const float w1 = 1.0f / (1.0f + __expf(v2 - v1));
            top_e[t] = i1 | (i2 << 4);
            top_w[t] = w1;
        }
    } else {
        // ---- We transpose: 64x64 tile per block ----
        const int idx = bid - 2048;
        const int e   = idx >> 8;
        const int rem = idx & 255;
        const int d0  = (rem >> 4) * 64;
        const int f0  = (rem & 15) * 64;
        const float* src = We + ((size_t)e * DMODEL + d0) * DMODEL + f0;
        #pragma unroll
        for (int i = 0; i < 16; ++i) {
            int ix = i * 256 + threadIdx.x;
            int dl = ix >> 6, fl = ix & 63;
            tile[fl][dl] = f32_to_bf16(src[(size_t)dl * DMODEL + fl]);
        }
        __syncthreads();
        unsigned short* dst = wt + ((size_t)e * DMODEL + f0) * DMODEL + d0;
        #pragma unroll
        for (int i = 0; i < 16; ++i) {
            int ix = i * 256 + threadIdx.x;
            int fl = ix >> 6, dl = ix & 63;
            dst[(size_t)fl * DMODEL + dl] = tile[fl][dl];
        }
    }
}

// ---------------------------------------------------------------------------
// Kernel 2: compact — grid (E, 32), single pass, zero atomics.
// Each block recomputes the global prefix for its chunk from top_e
// (8192 ints = 32 KB, L2-hit), then ballot-ordered scatter of its 256 tokens.
// ---------------------------------------------------------------------------
__global__ __launch_bounds__(256)
void compact(const int* __restrict__ top_e, const float* __restrict__ top_w,
             int* __restrict__ counts, int* __restrict__ toks,
             float* __restrict__ wgts, int* __restrict__ rows) {
    const int e    = blockIdx.x;
    const int c    = blockIdx.y;
    const int tid  = threadIdx.x;
    const int wave = tid >> 6;
    const int lane = tid & 63;

    __shared__ int sm[256];
    __shared__ int red[4];
    __shared__ int ws[4];

    // phase A: thread tid counts matches among tokens [tid*32, tid*32+32)
    int mc = 0;
    const int4* tp = reinterpret_cast<const int4*>(top_e) + tid * 8;
    #pragma unroll
    for (int i = 0; i < 8; ++i) {
        int4 v = tp[i];
        mc += (((v.x & 15) == e) || (((v.x >> 4) & 15) == e)) ? 1 : 0;
        mc += (((v.y & 15) == e) || (((v.y >> 4) & 15) == e)) ? 1 : 0;
        mc += (((v.z & 15) == e) || (((v.z >> 4) & 15) == e)) ? 1 : 0;
        mc += (((v.w & 15) == e) || (((v.w >> 4) & 15) == e)) ? 1 : 0;
    }
    sm[tid] = mc;
    __syncthreads();

    // phase B: base = sum of sm[0 .. c*8)  (tokens before this chunk)
    int v = (tid < c * 8) ? sm[tid] : 0;
    #pragma unroll
    for (int off = 1; off < 64; off <<= 1) v += __shfl_xor(v, off);
    if (lane == 0) red[wave] = v;
    __syncthreads();
    const int base = red[0] + red[1] + red[2] + red[3];

    // phase C: ballot scatter of this chunk's 256 tokens
    const int t  = c * 256 + tid;
    const int te = top_e[t];
    const int e1 = te & 15;
    const int e2 = (te >> 4) & 15;
    const bool m = (e1 == e) || (e2 == e);
    const unsigned long long b = __ballot(m);
    const int pos_in_wave = __popcll(b & ((1ull << lane) - 1ull));
    if (lane == 0) ws[wave] = __popcll(b);
    __syncthreads();

    int woff = base;
    #pragma unroll
    for (int i = 0; i < 4; ++i) if (i < wave) woff += ws[i];

    if (m) {
        const int pos = woff + pos_in_wave;
        const float w1 = top_w[t];
        toks[e * T_TOKENS + pos] = t;
        wgts[e * T_TOKENS + pos] = (e1 == e) ? w1 : 1.0f - w1;
        rows[t * 2 + ((e1 == e) ? 0 : 1)] = e * T_TOKENS + pos;
    }
    if (c == 31 && tid == 0)
        counts[e] = base + ws[0] + ws[1] + ws[2] + ws[3];
}

// ---------------------------------------------------------------------------
// Kernel 3: per-expert gather-GEMM — BK=32 double-buffer, stage-2-ahead,
// counted vmcnt(4). LDS = 2x16 KB = 32 KB -> still 4 blocks/CU (the r4
// failure was 64 KB dbuf -> 1-2 blocks/CU). Raw s_barrier (asm, memory
// clobber) so the prefetch loads are NEVER drained to 0 in the loop:
//   prologue: stage(b0,0); stage(b1,1)                      [8 in flight]
//   step t:   vmcnt(4)  // tile t landed, tile t+1 in flight
//             barrier; ds_read(b[t&1]) + 16 MFMA; barrier;
//             stage(b[t&1], t+2)                            [8 in flight]
// Race safety: bar1 follows every wave's own vmcnt(4) -> whole tile t in
// LDS; all ds_read results are consumed by MFMAs before bar2 (compiler
// lgkm deps) -> overwrite after bar2 is safe.
//   D[f][p] = sum_k wt[e][f][k] * xb[tok[p]][k]
// ---------------------------------------------------------------------------
__global__ __launch_bounds__(256)
void expert_gemm(const unsigned short* __restrict__ xb,
                 const unsigned short* __restrict__ wt,
                 const float* __restrict__ be,
                 const int* __restrict__ counts,
                 const int* __restrict__ toks,
                 const float* __restrict__ wgts,
                 unsigned short* __restrict__ hpart) {
    // XCD-aware remap: fy = flat % 8 -> each XCD owns one 128-feature slice,
    // wt working set 256 KB/XCD/expert = L2-resident (r6: +23%).
    const int flat = blockIdx.x + 64 * (blockIdx.y + 8 * blockIdx.z);
    const int fy   = flat & 7;
    const int rest = flat >> 3;
    const int tx   = rest & 63;
    const int e    = rest >> 6;

    const int cnt = counts[e];
    const int p0  = tx * BM;
    if (p0 >= cnt) return;
    const int f0  = fy * BN;

    __shared__ unsigned short lds_w[2][BN * BK];  // 2 x 8 KB, swizzled
    __shared__ unsigned short lds_x[2][BM * BK];  // 2 x 8 KB, swizzled
    __shared__ int   tok_s[BM];
    __shared__ float wgt_s[BM];

    const int tid  = threadIdx.x;
    const int wave = tid >> 6;
    const int lane = tid & 63;

    if (tid < BM) {
        int p = p0 + tid;
        if (p < cnt) {
            tok_s[tid] = toks[e * T_TOKENS + p];
            wgt_s[tid] = wgts[e * T_TOKENS + p];
        } else {
            tok_s[tid] = 0;
            wgt_s[tid] = 0.0f;
        }
    }
    __syncthreads();

    // Staging: tile row = 64 B (BK=32 bf16). One gload_lds(16B) covers 16
    // rows (4 lanes/row). Instr q = wave*2+s covers rows q*16..q*16+15.
    // Source pre-swizzled with (row&3)<<4 so linear LDS write lands swizzled.
    const char* wsrc[2];
    const char* xsrc[2];
    #pragma unroll
    for (int s = 0; s < 2; ++s) {
        const int q    = wave * 2 + s;
        const int row  = q * 16 + (lane >> 2);
        const int scol = ((lane & 3) << 4) ^ ((row & 3) << 4);
        wsrc[s] = (const char*)wt + ((size_t)(e * DMODEL + f0 + row) * DMODEL) * 2 + scol;
        xsrc[s] = (const char*)xb + ((size_t)tok_s[row] * DMODEL) * 2 + scol;
    }

    auto stage = [&](int buf, int step) {
        const size_t ko = (size_t)step * (BK * 2);
        #pragma unroll
        for (int s = 0; s < 2; ++s) {
            __builtin_amdgcn_global_load_lds(
                (const __attribute__((address_space(1))) void*)(wsrc[s] + ko),
                (__attribute__((address_space(3))) void*)((char*)lds_w[buf] + (wave * 2 + s) * 1024),
                16, 0, 0);
            __builtin_amdgcn_global_load_lds(
                (const __attribute__((address_space(1))) void*)(xsrc[s] + ko),
                (__attribute__((address_space(3))) void*)((char*)lds_x[buf] + (wave * 2 + s) * 1024),
                16, 0, 0);
        }
    };

    f32x4 acc[4][4] = {};

    const int wf = (wave & 1) * 64;   // feature sub-block of this wave
    const int wp = (wave >> 1) * 64;  // token sub-block of this wave

    auto compute = [&](int buf) {
        short8 afr[4], bfr[4];
        #pragma unroll
        for (int mi = 0; mi < 4; ++mi) {
            const int row = wf + mi * 16 + (lane & 15);
            const int kb  = ((lane >> 4) << 4) ^ ((row & 3) << 4);
            afr[mi] = *(const short8*)((const char*)lds_w[buf] + row * 64 + kb);
        }
        #pragma unroll
        for (int ni = 0; ni < 4; ++ni) {
            const int row = wp + ni * 16 + (lane & 15);
            const int kb  = ((lane >> 4) << 4) ^ ((row & 3) << 4);
            bfr[ni] = *(const short8*)((const char*)lds_x[buf] + row * 64 + kb);
        }
        #pragma unroll
        for (int mi = 0; mi < 4; ++mi)
            #pragma unroll
            for (int ni = 0; ni < 4; ++ni)
                asm("v_mfma_f32_16x16x32_bf16 %0, %1, %2, %0"
                    : "+v"(acc[mi][ni])
                    : "v"(afr[mi]), "v"(bfr[ni]));
    };

    // Prologue: two tiles in flight.
    stage(0, 0);
    stage(1, 1);

    #pragma unroll 1
    for (int t = 0; t < NSTEP - 1; ++t) {
        asm volatile("s_waitcnt vmcnt(4)" ::: "memory");  // tile t landed
        asm volatile("s_barrier" ::: "memory");           // visible to all
        compute(t & 1);
        asm volatile("s_barrier" ::: "memory");           // all done reading
        if (t + 2 < NSTEP) stage(t & 1, t + 2);           // refill, stay 8 deep
    }
    asm volatile("s_waitcnt vmcnt(0)" ::: "memory");
    asm volatile("s_barrier" ::: "memory");
    compute((NSTEP - 1) & 1);

    // Epilogue: lane holds D[f][p] frag: f = (lane>>4)*4 + r, p = lane&15.
    #pragma unroll
    for (int ni = 0; ni < 4; ++ni) {
        const int pl = wp + ni * 16 + (lane & 15);
        const int p  = p0 + pl;
        if (p >= cnt) continue;
        const float w = wgt_s[pl];
        unsigned short* hr = hpart + (size_t)(e * T_TOKENS + p) * DMODEL + f0 + wf;
        #pragma unroll
        for (int mi = 0; mi < 4; ++mi) {
            const int fb = mi * 16 + ((lane >> 4) << 2);
            const float* ber = be + (size_t)e * DMODEL + f0 + wf + fb;
            ushort4 o;
            float v0 = acc[mi][ni][0] + ber[0]; v0 = v0 > 0.f ? v0 : 0.f;
            float v1 = acc[mi][ni][1] + ber[1]; v1 = v1 > 0.f ? v1 : 0.f;
            float v2 = acc[mi][ni][2] + ber[2]; v2 = v2 > 0.f ? v2 : 0.f;
            float v3 = acc[mi][ni][3] + ber[3]; v3 = v3 > 0.f ? v3 : 0.f;
            o.x = f32_to_bf16(v0 * w);
            o.y = f32_to_bf16(v1 * w);
            o.z = f32_to_bf16(v2 * w);
            o.w = f32_to_bf16(v3 * w);
            *reinterpret_cast<ushort4*>(hr + fb) = o;
        }
    }
}

// ---------------------------------------------------------------------------
// Kernel 4: combine — y[t] = hpart[rows[t][0]] + hpart[rows[t][1]]
// ---------------------------------------------------------------------------
__global__ __launch_bounds__(256)
void combine(const unsigned short* __restrict__ hpart,
             const int* __restrict__ rows,
             float* __restrict__ y) {
    const int t = blockIdx.x;
    const int r0 = rows[t * 2 + 0];
    const int r1 = rows[t * 2 + 1];
    const int f = threadIdx.x * 4;
    ushort4 a = *reinterpret_cast<const ushort4*>(hpart + (size_t)r0 * DMODEL + f);
    ushort4 b = *reinterpret_cast<const ushort4*>(hpart + (size_t)r1 * DMODEL + f);
    float4 o;
    o.x = __builtin_bit_cast(float, (unsigned)a.x << 16) + __builtin_bit_cast(float, (unsigned)b.x << 16);
    o.y = __builtin_bit_cast(float, (unsigned)a.y << 16) + __builtin_bit_cast(float, (unsigned)b.y << 16);
    o.z = __builtin_bit_cast(float, (unsigned)a.z << 16) + __builtin_bit_cast(float, (unsigned)b.z << 16);
    o.w = __builtin_bit_cast(float, (unsigned)a.w << 16) + __builtin_bit_cast(float, (unsigned)b.w << 16);
    *reinterpret_cast<float4*>(y + (size_t)t * DMODEL + f) = o;
}

// ---------------------------------------------------------------------------
extern "C" void kernel_launch(void* const* d_in, const int* in_sizes, int n_in,
                              void* d_out, int out_size, void* d_ws, size_t ws_size,
                              hipStream_t stream) {
    (void)in_sizes; (void)n_in; (void)out_size; (void)ws_size;
    const float* x  = (const float*)d_in[0];
    const float* Wg = (const float*)d_in[1];
    const float* We = (const float*)d_in[2];
    const float* be = (const float*)d_in[3];
    float* y = (float*)d_out;

    char* ws = (char*)d_ws;
    unsigned short* xb     = (unsigned short*)(ws);                       // 16 MB
    unsigned short* wt     = (unsigned short*)(ws + (16u << 20));         // 16 MB
    size_t off = (32u << 20);
    int*   counts = (int*)(ws + off);    off += 1024;
    int*   toks   = (int*)(ws + off);    off += (size_t)NEXP * T_TOKENS * 4;
    float* wgts   = (float*)(ws + off);  off += (size_t)NEXP * T_TOKENS * 4;
    int*   rows   = (int*)(ws + off);    off += (size_t)T_TOKENS * 2 * 4;
    int*   top_e  = (int*)(ws + off);    off += (size_t)T_TOKENS * 4;
    float* top_w  = (float*)(ws + off);
    unsigned short* hpart = (unsigned short*)(ws + (34u << 20));          // 32 MB

    prep<<<dim3(4096), 256, 0, stream>>>(x, Wg, We, xb, wt, top_e, top_w);
    compact<<<dim3(NEXP, 32), 256, 0, stream>>>(top_e, top_w, counts, toks, wgts, rows);
    expert_gemm<<<dim3(T_TOKENS / BM, DMODEL / BN, NEXP), 256, 0, stream>>>(
        xb, wt, be, counts, toks, wgts, hpart);
    combine<<<dim3(T_TOKENS), 256, 0, stream>>>(hpart, rows, y);
}

// Round 10
// 113.405 us; speedup vs baseline: 1.0813x; 1.0813x over previous
//
#include <hip/hip_runtime.h>

#define T_TOKENS 8192
#define DMODEL   1024
#define NEXP     8

#define BM 128   // tokens per tile
#define BN 128   // features per tile
#define BK 64    // k per step (proven r6 config: single 32 KB buffer)
#define NSTEP (DMODEL / BK)

typedef float f32x4  __attribute__((ext_vector_type(4)));
typedef short short8 __attribute__((ext_vector_type(8)));

__device__ __forceinline__ unsigned short f32_to_bf16(float f) {
    unsigned int u = __builtin_bit_cast(unsigned int, f);
    unsigned int r = 0x7FFFu + ((u >> 16) & 1u);
    return (unsigned short)((u + r) >> 16);
}

// ---------------------------------------------------------------------------
// Kernel 1 (fused): blocks [0,2048) = gating (fp32 logits, top-2, x->bf16);
// blocks [2048,4096) = We [E][d][f] fp32 -> wt [E][f][d] bf16 transpose
// (vectorized: float4 reads, ushort4 tile reads, ushort4 global writes).
// ---------------------------------------------------------------------------
__global__ __launch_bounds__(256)
void prep(const float* __restrict__ x, const float* __restrict__ Wg,
          const float* __restrict__ We,
          unsigned short* __restrict__ xb, unsigned short* __restrict__ wt,
          int* __restrict__ top_e, float* __restrict__ top_w) {
    __shared__ unsigned short tile[64][72];
    const int bid = blockIdx.x;

    if (bid < 2048) {
        // ---- gating: one wave per token, 4 tokens/block ----
        const int wave = threadIdx.x >> 6;
        const int lane = threadIdx.x & 63;
        const int t = bid * 4 + wave;

        float lg[8];
        #pragma unroll
        for (int e = 0; e < 8; ++e) lg[e] = 0.0f;

        const float* xr = x + (size_t)t * DMODEL;
        unsigned short* xo = xb + (size_t)t * DMODEL;

        #pragma unroll
        for (int j = 0; j < 4; ++j) {
            const int d = j * 256 + lane * 4;
            float4 xv = *reinterpret_cast<const float4*>(xr + d);
            ushort4 o;
            o.x = f32_to_bf16(xv.x);
            o.y = f32_to_bf16(xv.y);
            o.z = f32_to_bf16(xv.z);
            o.w = f32_to_bf16(xv.w);
            *reinterpret_cast<ushort4*>(xo + d) = o;
            const float xs[4] = {xv.x, xv.y, xv.z, xv.w};
            #pragma unroll
            for (int c = 0; c < 4; ++c) {
                const float4 wlo = *reinterpret_cast<const float4*>(Wg + (size_t)(d + c) * 8);
                const float4 whi = *reinterpret_cast<const float4*>(Wg + (size_t)(d + c) * 8 + 4);
                lg[0] += xs[c] * wlo.x;  lg[1] += xs[c] * wlo.y;
                lg[2] += xs[c] * wlo.z;  lg[3] += xs[c] * wlo.w;
                lg[4] += xs[c] * whi.x;  lg[5] += xs[c] * whi.y;
                lg[6] += xs[c] * whi.z;  lg[7] += xs[c] * whi.w;
            }
        }
        #pragma unroll
        for (int off = 1; off < 64; off <<= 1) {
            #pragma unroll
            for (int e = 0; e < 8; ++e) lg[e] += __shfl_xor(lg[e], off);
        }

        if (lane == 0) {
            int i1 = 0; float v1 = lg[0];
            #pragma unroll
            for (int e = 1; e < 8; ++e) if (lg[e] > v1) { v1 = lg[e]; i1 = e; }
            int i2 = -1; float v2 = -1e30f;
            #pragma unroll
            for (int e = 0; e < 8; ++e) if (e != i1 && lg[e] > v2) { v2 = lg[e]; i2 = e; }
            const float w1 = 1.0f / (1.0f + __expf(v2 - v1));
            top_e[t] = i1 | (i2 << 4);
            top_w[t] = w1;
        }
    } else {
        // ---- We transpose: 64x64 tile per block, vectorized ----
        const int idx = bid - 2048;
        const int e   = idx >> 8;
        const int rem = idx & 255;
        const int d0  = (rem >> 4) * 64;
        const int f0  = (rem & 15) * 64;
        const float* src = We + ((size_t)e * DMODEL + d0) * DMODEL + f0;
        // phase 1: float4 coalesced reads, bf16 convert, scatter into tile
        #pragma unroll
        for (int j = 0; j < 4; ++j) {
            const int ix = j * 256 + threadIdx.x;   // 1024 float4 granules
            const int dl = ix >> 4;                 // 64 d rows
            const int fq = ix & 15;                 // 16 granules x 4 f
            float4 v = *reinterpret_cast<const float4*>(src + (size_t)dl * DMODEL + fq * 4);
            tile[fq * 4 + 0][dl] = f32_to_bf16(v.x);
            tile[fq * 4 + 1][dl] = f32_to_bf16(v.y);
            tile[fq * 4 + 2][dl] = f32_to_bf16(v.z);
            tile[fq * 4 + 3][dl] = f32_to_bf16(v.w);
        }
        __syncthreads();
        // phase 2: ushort4 tile reads (d-contig), ushort4 coalesced writes
        unsigned short* dst = wt + ((size_t)e * DMODEL + f0) * DMODEL + d0;
        #pragma unroll
        for (int j = 0; j < 4; ++j) {
            const int ix = j * 256 + threadIdx.x;
            const int fl = ix >> 4;
            const int dq = ix & 15;
            ushort4 v = *reinterpret_cast<const ushort4*>(&tile[fl][dq * 4]);
            *reinterpret_cast<ushort4*>(dst + (size_t)fl * DMODEL + dq * 4) = v;
        }
    }
}

// ---------------------------------------------------------------------------
// Kernel 2: compact — grid (E, 32), single pass, zero atomics.
// Each block recomputes the global prefix for its chunk from top_e
// (8192 ints = 32 KB, L2-hit), then ballot-ordered scatter of its 256 tokens.
// ---------------------------------------------------------------------------
__global__ __launch_bounds__(256)
void compact(const int* __restrict__ top_e, const float* __restrict__ top_w,
             int* __restrict__ counts, int* __restrict__ toks,
             float* __restrict__ wgts, int* __restrict__ rows) {
    const int e    = blockIdx.x;
    const int c    = blockIdx.y;
    const int tid  = threadIdx.x;
    const int wave = tid >> 6;
    const int lane = tid & 63;

    __shared__ int sm[256];
    __shared__ int red[4];
    __shared__ int ws[4];

    // phase A: thread tid counts matches among tokens [tid*32, tid*32+32)
    int mc = 0;
    const int4* tp = reinterpret_cast<const int4*>(top_e) + tid * 8;
    #pragma unroll
    for (int i = 0; i < 8; ++i) {
        int4 v = tp[i];
        mc += (((v.x & 15) == e) || (((v.x >> 4) & 15) == e)) ? 1 : 0;
        mc += (((v.y & 15) == e) || (((v.y >> 4) & 15) == e)) ? 1 : 0;
        mc += (((v.z & 15) == e) || (((v.z >> 4) & 15) == e)) ? 1 : 0;
        mc += (((v.w & 15) == e) || (((v.w >> 4) & 15) == e)) ? 1 : 0;
    }
    sm[tid] = mc;
    __syncthreads();

    // phase B: base = sum of sm[0 .. c*8)  (tokens before this chunk)
    int v = (tid < c * 8) ? sm[tid] : 0;
    #pragma unroll
    for (int off = 1; off < 64; off <<= 1) v += __shfl_xor(v, off);
    if (lane == 0) red[wave] = v;
    __syncthreads();
    const int base = red[0] + red[1] + red[2] + red[3];

    // phase C: ballot scatter of this chunk's 256 tokens
    const int t  = c * 256 + tid;
    const int te = top_e[t];
    const int e1 = te & 15;
    const int e2 = (te >> 4) & 15;
    const bool m = (e1 == e) || (e2 == e);
    const unsigned long long b = __ballot(m);
    const int pos_in_wave = __popcll(b & ((1ull << lane) - 1ull));
    if (lane == 0) ws[wave] = __popcll(b);
    __syncthreads();

    int woff = base;
    #pragma unroll
    for (int i = 0; i < 4; ++i) if (i < wave) woff += ws[i];

    if (m) {
        const int pos = woff + pos_in_wave;
        const float w1 = top_w[t];
        toks[e * T_TOKENS + pos] = t;
        wgts[e * T_TOKENS + pos] = (e1 == e) ? w1 : 1.0f - w1;
        rows[t * 2 + ((e1 == e) ? 0 : 1)] = e * T_TOKENS + pos;
    }
    if (c == 31 && tid == 0)
        counts[e] = base + ws[0] + ws[1] + ws[2] + ws[3];
}

// ---------------------------------------------------------------------------
// Kernel 3: per-expert gather-GEMM — REVERTED to the proven r6 structure:
// BK=64, SINGLE 32 KB LDS buffer (33.8 KB total -> 4 blocks/CU, 16 waves/CU),
// 2x __syncthreads per K-step, (row&7)<<4 swizzle (0 bank conflicts), and
// XCD f-slice remap (fy = flat%8 -> wt slice 256 KB/XCD = L2-resident).
// The r9 BK=32 dbuf + counted-vmcnt regressed: wrong swizzle at 64 B rows
// (4-way conflict, 4.3M) + 2x barrier count — T4 only pays inside an 8-phase
// schedule (m218/m230), not grafted onto a 2-phase loop.
//   D[f][p] = sum_k wt[e][f][k] * xb[tok[p]][k]
// ---------------------------------------------------------------------------
__global__ __launch_bounds__(256)
void expert_gemm(const unsigned short* __restrict__ xb,
                 const unsigned short* __restrict__ wt,
                 const float* __restrict__ be,
                 const int* __restrict__ counts,
                 const int* __restrict__ toks,
                 const float* __restrict__ wgts,
                 unsigned short* __restrict__ hpart) {
    const int flat = blockIdx.x + 64 * (blockIdx.y + 8 * blockIdx.z);
    const int fy   = flat & 7;          // feature tile: constant per XCD
    const int rest = flat >> 3;
    const int tx   = rest & 63;         // token tile
    const int e    = rest >> 6;         // expert: outermost

    const int cnt = counts[e];
    const int p0  = tx * BM;
    if (p0 >= cnt) return;
    const int f0  = fy * BN;

    __shared__ unsigned short lds_w[BN * BK];  // [f][k], swizzled, 16 KB
    __shared__ unsigned short lds_x[BM * BK];  // [p][k], swizzled, 16 KB
    __shared__ int   tok_s[BM];
    __shared__ float wgt_s[BM];

    const int tid  = threadIdx.x;
    const int wave = tid >> 6;
    const int lane = tid & 63;

    if (tid < BM) {
        int p = p0 + tid;
        if (p < cnt) {
            tok_s[tid] = toks[e * T_TOKENS + p];
            wgt_s[tid] = wgts[e * T_TOKENS + p];
        } else {
            tok_s[tid] = 0;
            wgt_s[tid] = 0.0f;
        }
    }
    __syncthreads();

    // Per-lane staging sources, pre-swizzled so the linear global_load_lds
    // write produces the XOR-swizzled LDS layout.
    const char* wsrc[4];
    const char* xsrc[4];
    #pragma unroll
    for (int s = 0; s < 4; ++s) {
        const int q    = wave * 4 + s;
        const int row  = q * 8 + (lane >> 3);
        const int scol = ((lane & 7) << 4) ^ ((row & 7) << 4);
        wsrc[s] = (const char*)wt + ((size_t)(e * DMODEL + f0 + row) * DMODEL) * 2 + scol;
        xsrc[s] = (const char*)xb + ((size_t)tok_s[row] * DMODEL) * 2 + scol;
    }

    f32x4 acc[4][4] = {};

    const int wf = (wave & 1) * 64;   // feature sub-block of this wave
    const int wp = (wave >> 1) * 64;  // token sub-block of this wave

    #pragma unroll 1
    for (int t = 0; t < NSTEP; ++t) {
        const size_t ko = (size_t)t * BK * 2;
        #pragma unroll
        for (int s = 0; s < 4; ++s) {
            __builtin_amdgcn_global_load_lds(
                (const __attribute__((address_space(1))) void*)(wsrc[s] + ko),
                (__attribute__((address_space(3))) void*)((char*)lds_w + (wave * 4 + s) * 1024),
                16, 0, 0);
            __builtin_amdgcn_global_load_lds(
                (const __attribute__((address_space(1))) void*)(xsrc[s] + ko),
                (__attribute__((address_space(3))) void*)((char*)lds_x + (wave * 4 + s) * 1024),
                16, 0, 0);
        }
        __syncthreads();   // drains vmcnt -> tile visible to all waves

        #pragma unroll
        for (int kk = 0; kk < 2; ++kk) {
            short8 afr[4], bfr[4];
            #pragma unroll
            for (int mi = 0; mi < 4; ++mi) {
                const int row = wf + mi * 16 + (lane & 15);
                const int kb  = (kk * 64 + ((lane >> 4) << 4)) ^ ((row & 7) << 4);
                afr[mi] = *(const short8*)((const char*)lds_w + row * 128 + kb);
            }
            #pragma unroll
            for (int ni = 0; ni < 4; ++ni) {
                const int row = wp + ni * 16 + (lane & 15);
                const int kb  = (kk * 64 + ((lane >> 4) << 4)) ^ ((row & 7) << 4);
                bfr[ni] = *(const short8*)((const char*)lds_x + row * 128 + kb);
            }
            #pragma unroll
            for (int mi = 0; mi < 4; ++mi)
                #pragma unroll
                for (int ni = 0; ni < 4; ++ni)
                    asm("v_mfma_f32_16x16x32_bf16 %0, %1, %2, %0"
                        : "+v"(acc[mi][ni])
                        : "v"(afr[mi]), "v"(bfr[ni]));
        }
        __syncthreads();   // all waves done reading before next overwrite
    }

    // Epilogue: lane holds D[f][p] frag: f = (lane>>4)*4 + r, p = lane&15.
    #pragma unroll
    for (int ni = 0; ni < 4; ++ni) {
        const int pl = wp + ni * 16 + (lane & 15);
        const int p  = p0 + pl;
        if (p >= cnt) continue;
        const float w = wgt_s[pl];
        unsigned short* hr = hpart + (size_t)(e * T_TOKENS + p) * DMODEL + f0 + wf;
        #pragma unroll
        for (int mi = 0; mi < 4; ++mi) {
            const int fb = mi * 16 + ((lane >> 4) << 2);
            const float* ber = be + (size_t)e * DMODEL + f0 + wf + fb;
            ushort4 o;
            float v0 = acc[mi][ni][0] + ber[0]; v0 = v0 > 0.f ? v0 : 0.f;
            float v1 = acc[mi][ni][1] + ber[1]; v1 = v1 > 0.f ? v1 : 0.f;
            float v2 = acc[mi][ni][2] + ber[2]; v2 = v2 > 0.f ? v2 : 0.f;
            float v3 = acc[mi][ni][3] + ber[3]; v3 = v3 > 0.f ? v3 : 0.f;
            o.x = f32_to_bf16(v0 * w);
            o.y = f32_to_bf16(v1 * w);
            o.z = f32_to_bf16(v2 * w);
            o.w = f32_to_bf16(v3 * w);
            *reinterpret_cast<ushort4*>(hr + fb) = o;
        }
    }
}

// ---------------------------------------------------------------------------
// Kernel 4: combine — y[t] = hpart[rows[t][0]] + hpart[rows[t][1]]
// ---------------------------------------------------------------------------
__global__ __launch_bounds__(256)
void combine(const unsigned short* __restrict__ hpart,
             const int* __restrict__ rows,
             float* __restrict__ y) {
    const int t = blockIdx.x;
    const int r0 = rows[t * 2 + 0];
    const int r1 = rows[t * 2 + 1];
    const int f = threadIdx.x * 4;
    ushort4 a = *reinterpret_cast<const ushort4*>(hpart + (size_t)r0 * DMODEL + f);
    ushort4 b = *reinterpret_cast<const ushort4*>(hpart + (size_t)r1 * DMODEL + f);
    float4 o;
    o.x = __builtin_bit_cast(float, (unsigned)a.x << 16) + __builtin_bit_cast(float, (unsigned)b.x << 16);
    o.y = __builtin_bit_cast(float, (unsigned)a.y << 16) + __builtin_bit_cast(float, (unsigned)b.y << 16);
    o.z = __builtin_bit_cast(float, (unsigned)a.z << 16) + __builtin_bit_cast(float, (unsigned)b.z << 16);
    o.w = __builtin_bit_cast(float, (unsigned)a.w << 16) + __builtin_bit_cast(float, (unsigned)b.w << 16);
    *reinterpret_cast<float4*>(y + (size_t)t * DMODEL + f) = o;
}

// ---------------------------------------------------------------------------
extern "C" void kernel_launch(void* const* d_in, const int* in_sizes, int n_in,
                              void* d_out, int out_size, void* d_ws, size_t ws_size,
                              hipStream_t stream) {
    (void)in_sizes; (void)n_in; (void)out_size; (void)ws_size;
    const float* x  = (const float*)d_in[0];
    const float* Wg = (const float*)d_in[1];
    const float* We = (const float*)d_in[2];
    const float* be = (const float*)d_in[3];
    float* y = (float*)d_out;

    char* ws = (char*)d_ws;
    unsigned short* xb     = (unsigned short*)(ws);                       // 16 MB
    unsigned short* wt     = (unsigned short*)(ws + (16u << 20));         // 16 MB
    size_t off = (32u << 20);
    int*   counts = (int*)(ws + off);    off += 1024;
    int*   toks   = (int*)(ws + off);    off += (size_t)NEXP * T_TOKENS * 4;
    float* wgts   = (float*)(ws + off);  off += (size_t)NEXP * T_TOKENS * 4;
    int*   rows   = (int*)(ws + off);    off += (size_t)T_TOKENS * 2 * 4;
    int*   top_e  = (int*)(ws + off);    off += (size_t)T_TOKENS * 4;
    float* top_w  = (float*)(ws + off);
    unsigned short* hpart = (unsigned short*)(ws + (34u << 20));          // 32 MB

    prep<<<dim3(4096), 256, 0, stream>>>(x, Wg, We, xb, wt, top_e, top_w);
    compact<<<dim3(NEXP, 32), 256, 0, stream>>>(top_e, top_w, counts, toks, wgts, rows);
    expert_gemm<<<dim3(T_TOKENS / BM, DMODEL / BN, NEXP), 256, 0, stream>>>(
        xb, wt, be, counts, toks, wgts, hpart);
    combine<<<dim3(T_TOKENS), 256, 0, stream>>>(hpart, rows, y);
}

// Round 11
// 107.040 us; speedup vs baseline: 1.1456x; 1.0595x over previous
//
#include <hip/hip_runtime.h>

#define T_TOKENS 8192
#define DMODEL   1024
#define NEXP     8

#define BM 128   // tokens per tile
#define BN 128   // features per tile
#define BK 64    // k per step (proven r6 config: single 32 KB buffer)
#define NSTEP (DMODEL / BK)

typedef float f32x4  __attribute__((ext_vector_type(4)));
typedef short short8 __attribute__((ext_vector_type(8)));

__device__ __forceinline__ unsigned short f32_to_bf16(float f) {
    unsigned int u = __builtin_bit_cast(unsigned int, f);
    unsigned int r = 0x7FFFu + ((u >> 16) & 1u);
    return (unsigned short)((u + r) >> 16);
}

// ---------------------------------------------------------------------------
// Kernel 1 (fused): blocks [0,2048) = gating (fp32 logits, top-2, x->bf16);
// blocks [2048,4096) = We [E][d][f] fp32 -> wt [E][f][d] bf16 transpose
// (vectorized: float4 reads, ushort4 tile reads, ushort4 global writes).
// ---------------------------------------------------------------------------
__global__ __launch_bounds__(256)
void prep(const float* __restrict__ x, const float* __restrict__ Wg,
          const float* __restrict__ We,
          unsigned short* __restrict__ xb, unsigned short* __restrict__ wt,
          int* __restrict__ top_e, float* __restrict__ top_w) {
    __shared__ unsigned short tile[64][72];
    const int bid = blockIdx.x;

    if (bid < 2048) {
        // ---- gating: one wave per token, 4 tokens/block ----
        const int wave = threadIdx.x >> 6;
        const int lane = threadIdx.x & 63;
        const int t = bid * 4 + wave;

        float lg[8];
        #pragma unroll
        for (int e = 0; e < 8; ++e) lg[e] = 0.0f;

        const float* xr = x + (size_t)t * DMODEL;
        unsigned short* xo = xb + (size_t)t * DMODEL;

        #pragma unroll
        for (int j = 0; j < 4; ++j) {
            const int d = j * 256 + lane * 4;
            float4 xv = *reinterpret_cast<const float4*>(xr + d);
            ushort4 o;
            o.x = f32_to_bf16(xv.x);
            o.y = f32_to_bf16(xv.y);
            o.z = f32_to_bf16(xv.z);
            o.w = f32_to_bf16(xv.w);
            *reinterpret_cast<ushort4*>(xo + d) = o;
            const float xs[4] = {xv.x, xv.y, xv.z, xv.w};
            #pragma unroll
            for (int c = 0; c < 4; ++c) {
                const float4 wlo = *reinterpret_cast<const float4*>(Wg + (size_t)(d + c) * 8);
                const float4 whi = *reinterpret_cast<const float4*>(Wg + (size_t)(d + c) * 8 + 4);
                lg[0] += xs[c] * wlo.x;  lg[1] += xs[c] * wlo.y;
                lg[2] += xs[c] * wlo.z;  lg[3] += xs[c] * wlo.w;
                lg[4] += xs[c] * whi.x;  lg[5] += xs[c] * whi.y;
                lg[6] += xs[c] * whi.z;  lg[7] += xs[c] * whi.w;
            }
        }
        #pragma unroll
        for (int off = 1; off < 64; off <<= 1) {
            #pragma unroll
            for (int e = 0; e < 8; ++e) lg[e] += __shfl_xor(lg[e], off);
        }

        if (lane == 0) {
            int i1 = 0; float v1 = lg[0];
            #pragma unroll
            for (int e = 1; e < 8; ++e) if (lg[e] > v1) { v1 = lg[e]; i1 = e; }
            int i2 = -1; float v2 = -1e30f;
            #pragma unroll
            for (int e = 0; e < 8; ++e) if (e != i1 && lg[e] > v2) { v2 = lg[e]; i2 = e; }
            const float w1 = 1.0f / (1.0f + __expf(v2 - v1));
            top_e[t] = i1 | (i2 << 4);
            top_w[t] = w1;
        }
    } else {
        // ---- We transpose: 64x64 tile per block, vectorized ----
        const int idx = bid - 2048;
        const int e   = idx >> 8;
        const int rem = idx & 255;
        const int d0  = (rem >> 4) * 64;
        const int f0  = (rem & 15) * 64;
        const float* src = We + ((size_t)e * DMODEL + d0) * DMODEL + f0;
        // phase 1: float4 coalesced reads, bf16 convert, scatter into tile
        #pragma unroll
        for (int j = 0; j < 4; ++j) {
            const int ix = j * 256 + threadIdx.x;   // 1024 float4 granules
            const int dl = ix >> 4;                 // 64 d rows
            const int fq = ix & 15;                 // 16 granules x 4 f
            float4 v = *reinterpret_cast<const float4*>(src + (size_t)dl * DMODEL + fq * 4);
            tile[fq * 4 + 0][dl] = f32_to_bf16(v.x);
            tile[fq * 4 + 1][dl] = f32_to_bf16(v.y);
            tile[fq * 4 + 2][dl] = f32_to_bf16(v.z);
            tile[fq * 4 + 3][dl] = f32_to_bf16(v.w);
        }
        __syncthreads();
        // phase 2: ushort4 tile reads (d-contig), ushort4 coalesced writes
        unsigned short* dst = wt + ((size_t)e * DMODEL + f0) * DMODEL + d0;
        #pragma unroll
        for (int j = 0; j < 4; ++j) {
            const int ix = j * 256 + threadIdx.x;
            const int fl = ix >> 4;
            const int dq = ix & 15;
            ushort4 v = *reinterpret_cast<const ushort4*>(&tile[fl][dq * 4]);
            *reinterpret_cast<ushort4*>(dst + (size_t)fl * DMODEL + dq * 4) = v;
        }
    }
}

// ---------------------------------------------------------------------------
// Kernel 2: compact — grid (E, 32), single pass, zero atomics.
// ---------------------------------------------------------------------------
__global__ __launch_bounds__(256)
void compact(const int* __restrict__ top_e, const float* __restrict__ top_w,
             int* __restrict__ counts, int* __restrict__ toks,
             float* __restrict__ wgts, int* __restrict__ rows) {
    const int e    = blockIdx.x;
    const int c    = blockIdx.y;
    const int tid  = threadIdx.x;
    const int wave = tid >> 6;
    const int lane = tid & 63;

    __shared__ int sm[256];
    __shared__ int red[4];
    __shared__ int ws[4];

    // phase A: thread tid counts matches among tokens [tid*32, tid*32+32)
    int mc = 0;
    const int4* tp = reinterpret_cast<const int4*>(top_e) + tid * 8;
    #pragma unroll
    for (int i = 0; i < 8; ++i) {
        int4 v = tp[i];
        mc += (((v.x & 15) == e) || (((v.x >> 4) & 15) == e)) ? 1 : 0;
        mc += (((v.y & 15) == e) || (((v.y >> 4) & 15) == e)) ? 1 : 0;
        mc += (((v.z & 15) == e) || (((v.z >> 4) & 15) == e)) ? 1 : 0;
        mc += (((v.w & 15) == e) || (((v.w >> 4) & 15) == e)) ? 1 : 0;
    }
    sm[tid] = mc;
    __syncthreads();

    // phase B: base = sum of sm[0 .. c*8)
    int v = (tid < c * 8) ? sm[tid] : 0;
    #pragma unroll
    for (int off = 1; off < 64; off <<= 1) v += __shfl_xor(v, off);
    if (lane == 0) red[wave] = v;
    __syncthreads();
    const int base = red[0] + red[1] + red[2] + red[3];

    // phase C: ballot scatter of this chunk's 256 tokens
    const int t  = c * 256 + tid;
    const int te = top_e[t];
    const int e1 = te & 15;
    const int e2 = (te >> 4) & 15;
    const bool m = (e1 == e) || (e2 == e);
    const unsigned long long b = __ballot(m);
    const int pos_in_wave = __popcll(b & ((1ull << lane) - 1ull));
    if (lane == 0) ws[wave] = __popcll(b);
    __syncthreads();

    int woff = base;
    #pragma unroll
    for (int i = 0; i < 4; ++i) if (i < wave) woff += ws[i];

    if (m) {
        const int pos = woff + pos_in_wave;
        const float w1 = top_w[t];
        toks[e * T_TOKENS + pos] = t;
        wgts[e * T_TOKENS + pos] = (e1 == e) ? w1 : 1.0f - w1;
        rows[t * 2 + ((e1 == e) ? 0 : 1)] = e * T_TOKENS + pos;
    }
    if (c == 31 && tid == 0)
        counts[e] = base + ws[0] + ws[1] + ws[2] + ws[3];
}

// ---------------------------------------------------------------------------
// Kernel 3: per-expert gather-GEMM (r6/r10 proven structure: BK=64, single
// 32 KB buffer, 2x __syncthreads/K-step, (row&7)<<4 swizzle) with
// EXPERT-major XCD remap, fy-fast ordering:
//   e = flat%8  -> each XCD owns ONE expert: wt slice = 2 MB, L2-resident.
//   fy = (flat>>3)%8 fast, tx slow -> 8 consecutive blocks on an XCD reuse
//   the SAME 128-token xb tile (256 KB hot) across all 8 f-tiles, so each
//   xb row is fetched once per XCD from L3 and served 8x from L2.
// r10's f-slice remap had wt resident but xb re-fetched 8x (FETCH 110 MB vs
// 48 MB unique) -> every K-step barrier waited on L3/HBM-class latency.
// Balance: cnt_e ~= 2048 +- 2% (multinomial), so per-XCD work is even.
//   D[f][p] = sum_k wt[e][f][k] * xb[tok[p]][k]
// ---------------------------------------------------------------------------
__global__ __launch_bounds__(256)
void expert_gemm(const unsigned short* __restrict__ xb,
                 const unsigned short* __restrict__ wt,
                 const float* __restrict__ be,
                 const int* __restrict__ counts,
                 const int* __restrict__ toks,
                 const float* __restrict__ wgts,
                 unsigned short* __restrict__ hpart) {
    const int flat = blockIdx.x + 64 * (blockIdx.y + 8 * blockIdx.z);
    const int e    = flat & 7;          // expert: constant per XCD
    const int rest = flat >> 3;
    const int fy   = rest & 7;          // feature tile: cycles fast
    const int tx   = rest >> 3;         // token tile: slow

    const int cnt = counts[e];
    const int p0  = tx * BM;
    if (p0 >= cnt) return;
    const int f0  = fy * BN;

    __shared__ unsigned short lds_w[BN * BK];  // [f][k], swizzled, 16 KB
    __shared__ unsigned short lds_x[BM * BK];  // [p][k], swizzled, 16 KB
    __shared__ int   tok_s[BM];
    __shared__ float wgt_s[BM];

    const int tid  = threadIdx.x;
    const int wave = tid >> 6;
    const int lane = tid & 63;

    if (tid < BM) {
        int p = p0 + tid;
        if (p < cnt) {
            tok_s[tid] = toks[e * T_TOKENS + p];
            wgt_s[tid] = wgts[e * T_TOKENS + p];
        } else {
            tok_s[tid] = 0;
            wgt_s[tid] = 0.0f;
        }
    }
    __syncthreads();

    // Per-lane staging sources, pre-swizzled so the linear global_load_lds
    // write produces the XOR-swizzled LDS layout.
    const char* wsrc[4];
    const char* xsrc[4];
    #pragma unroll
    for (int s = 0; s < 4; ++s) {
        const int q    = wave * 4 + s;
        const int row  = q * 8 + (lane >> 3);
        const int scol = ((lane & 7) << 4) ^ ((row & 7) << 4);
        wsrc[s] = (const char*)wt + ((size_t)(e * DMODEL + f0 + row) * DMODEL) * 2 + scol;
        xsrc[s] = (const char*)xb + ((size_t)tok_s[row] * DMODEL) * 2 + scol;
    }

    f32x4 acc[4][4] = {};

    const int wf = (wave & 1) * 64;   // feature sub-block of this wave
    const int wp = (wave >> 1) * 64;  // token sub-block of this wave

    #pragma unroll 1
    for (int t = 0; t < NSTEP; ++t) {
        const size_t ko = (size_t)t * BK * 2;
        #pragma unroll
        for (int s = 0; s < 4; ++s) {
            __builtin_amdgcn_global_load_lds(
                (const __attribute__((address_space(1))) void*)(wsrc[s] + ko),
                (__attribute__((address_space(3))) void*)((char*)lds_w + (wave * 4 + s) * 1024),
                16, 0, 0);
            __builtin_amdgcn_global_load_lds(
                (const __attribute__((address_space(1))) void*)(xsrc[s] + ko),
                (__attribute__((address_space(3))) void*)((char*)lds_x + (wave * 4 + s) * 1024),
                16, 0, 0);
        }
        __syncthreads();   // drains vmcnt -> tile visible to all waves

        #pragma unroll
        for (int kk = 0; kk < 2; ++kk) {
            short8 afr[4], bfr[4];
            #pragma unroll
            for (int mi = 0; mi < 4; ++mi) {
                const int row = wf + mi * 16 + (lane & 15);
                const int kb  = (kk * 64 + ((lane >> 4) << 4)) ^ ((row & 7) << 4);
                afr[mi] = *(const short8*)((const char*)lds_w + row * 128 + kb);
            }
            #pragma unroll
            for (int ni = 0; ni < 4; ++ni) {
                const int row = wp + ni * 16 + (lane & 15);
                const int kb  = (kk * 64 + ((lane >> 4) << 4)) ^ ((row & 7) << 4);
                bfr[ni] = *(const short8*)((const char*)lds_x + row * 128 + kb);
            }
            #pragma unroll
            for (int mi = 0; mi < 4; ++mi)
                #pragma unroll
                for (int ni = 0; ni < 4; ++ni)
                    asm("v_mfma_f32_16x16x32_bf16 %0, %1, %2, %0"
                        : "+v"(acc[mi][ni])
                        : "v"(afr[mi]), "v"(bfr[ni]));
        }
        __syncthreads();   // all waves done reading before next overwrite
    }

    // Epilogue: lane holds D[f][p] frag: f = (lane>>4)*4 + r, p = lane&15.
    #pragma unroll
    for (int ni = 0; ni < 4; ++ni) {
        const int pl = wp + ni * 16 + (lane & 15);
        const int p  = p0 + pl;
        if (p >= cnt) continue;
        const float w = wgt_s[pl];
        unsigned short* hr = hpart + (size_t)(e * T_TOKENS + p) * DMODEL + f0 + wf;
        #pragma unroll
        for (int mi = 0; mi < 4; ++mi) {
            const int fb = mi * 16 + ((lane >> 4) << 2);
            const float* ber = be + (size_t)e * DMODEL + f0 + wf + fb;
            ushort4 o;
            float v0 = acc[mi][ni][0] + ber[0]; v0 = v0 > 0.f ? v0 : 0.f;
            float v1 = acc[mi][ni][1] + ber[1]; v1 = v1 > 0.f ? v1 : 0.f;
            float v2 = acc[mi][ni][2] + ber[2]; v2 = v2 > 0.f ? v2 : 0.f;
            float v3 = acc[mi][ni][3] + ber[3]; v3 = v3 > 0.f ? v3 : 0.f;
            o.x = f32_to_bf16(v0 * w);
            o.y = f32_to_bf16(v1 * w);
            o.z = f32_to_bf16(v2 * w);
            o.w = f32_to_bf16(v3 * w);
            *reinterpret_cast<ushort4*>(hr + fb) = o;
        }
    }
}

// ---------------------------------------------------------------------------
// Kernel 4: combine — y[t] = hpart[rows[t][0]] + hpart[rows[t][1]]
// ---------------------------------------------------------------------------
__global__ __launch_bounds__(256)
void combine(const unsigned short* __restrict__ hpart,
             const int* __restrict__ rows,
             float* __restrict__ y) {
    const int t = blockIdx.x;
    const int r0 = rows[t * 2 + 0];
    const int r1 = rows[t * 2 + 1];
    const int f = threadIdx.x * 4;
    ushort4 a = *reinterpret_cast<const ushort4*>(hpart + (size_t)r0 * DMODEL + f);
    ushort4 b = *reinterpret_cast<const ushort4*>(hpart + (size_t)r1 * DMODEL + f);
    float4 o;
    o.x = __builtin_bit_cast(float, (unsigned)a.x << 16) + __builtin_bit_cast(float, (unsigned)b.x << 16);
    o.y = __builtin_bit_cast(float, (unsigned)a.y << 16) + __builtin_bit_cast(float, (unsigned)b.y << 16);
    o.z = __builtin_bit_cast(float, (unsigned)a.z << 16) + __builtin_bit_cast(float, (unsigned)b.z << 16);
    o.w = __builtin_bit_cast(float, (unsigned)a.w << 16) + __builtin_bit_cast(float, (unsigned)b.w << 16);
    *reinterpret_cast<float4*>(y + (size_t)t * DMODEL + f) = o;
}

// ---------------------------------------------------------------------------
extern "C" void kernel_launch(void* const* d_in, const int* in_sizes, int n_in,
                              void* d_out, int out_size, void* d_ws, size_t ws_size,
                              hipStream_t stream) {
    (void)in_sizes; (void)n_in; (void)out_size; (void)ws_size;
    const float* x  = (const float*)d_in[0];
    const float* Wg = (const float*)d_in[1];
    const float* We = (const float*)d_in[2];
    const float* be = (const float*)d_in[3];
    float* y = (float*)d_out;

    char* ws = (char*)d_ws;
    unsigned short* xb     = (unsigned short*)(ws);                       // 16 MB
    unsigned short* wt     = (unsigned short*)(ws + (16u << 20));         // 16 MB
    size_t off = (32u << 20);
    int*   counts = (int*)(ws + off);    off += 1024;
    int*   toks   = (int*)(ws + off);    off += (size_t)NEXP * T_TOKENS * 4;
    float* wgts   = (float*)(ws + off);  off += (size_t)NEXP * T_TOKENS * 4;
    int*   rows   = (int*)(ws + off);    off += (size_t)T_TOKENS * 2 * 4;
    int*   top_e  = (int*)(ws + off);    off += (size_t)T_TOKENS * 4;
    float* top_w  = (float*)(ws + off);
    unsigned short* hpart = (unsigned short*)(ws + (34u << 20));          // 32 MB

    prep<<<dim3(4096), 256, 0, stream>>>(x, Wg, We, xb, wt, top_e, top_w);
    compact<<<dim3(NEXP, 32), 256, 0, stream>>>(top_e, top_w, counts, toks, wgts, rows);
    expert_gemm<<<dim3(T_TOKENS / BM, DMODEL / BN, NEXP), 256, 0, stream>>>(
        xb, wt, be, counts, toks, wgts, hpart);
    combine<<<dim3(T_TOKENS), 256, 0, stream>>>(hpart, rows, y);
}